// Round 8
// baseline (6106.767 us; speedup 1.0000x reference)
//
#include <hip/hip_runtime.h>
#include <math.h>

// Problem constants
#define NN 40000
#define NE 256000

// Workspace layout (floats), total 61,640,000 floats = 246.6 MB
//  acc : 40000*1152 = 46,080,000   [r|b|l] scatter accumulators
//  hp  : 40000*384  = 15,360,000   projected node features; REUSED as hg
//  cls : 40000*5    =    200,000   softmax probs
static const size_t ACC_OFF = 0;
static const size_t HP_OFF  = 46080000;
static const size_t CLS_OFF = 61440000;
#define ACC_FLOATS 46080000

// ---------------------------------------------------------------------------
__global__ __launch_bounds__(256) void k_zero(float4* __restrict__ p, int n4)
{
    int stride = gridDim.x * 256;
    for (int i = blockIdx.x * 256 + threadIdx.x; i < n4; i += stride)
        p[i] = make_float4(0.f, 0.f, 0.f, 0.f);
}

// ---------------------------------------------------------------------------
// Kernel A: fused projections, register-blocked (unchanged).
// ---------------------------------------------------------------------------
__global__ __launch_bounds__(192) void k_proj(
    const float* __restrict__ h,
    const float* __restrict__ Wp0, const float* __restrict__ bp0,
    const float* __restrict__ gp0, const float* __restrict__ bep0,
    const float* __restrict__ Wp1, const float* __restrict__ bp1,
    const float* __restrict__ gp1, const float* __restrict__ bep1,
    float* __restrict__ hp)
{
    __shared__ __align__(16) float xs[384 * 16];   // [c][n], 24.6 KB
    __shared__ float2 stats0[16], stats1[16];
    const int tid = threadIdx.x;
    const int n0  = blockIdx.x * 16;
    const int jg  = tid % 48;
    const int nt  = tid / 48;
    const int j0  = jg * 4;

    for (int idx = tid; idx < 384 * 16; idx += 192) {
        int n = idx & 15, c = idx >> 4;
        xs[c * 16 + n] = h[(size_t)(n0 + n) * 384 + c];
    }
    __syncthreads();

    float a0[4][4], a1[4][4];
    #pragma unroll
    for (int r = 0; r < 4; ++r)
        #pragma unroll
        for (int n = 0; n < 4; ++n) { a0[r][n] = 0.f; a1[r][n] = 0.f; }

    #pragma unroll 2
    for (int k = 0; k < 300; ++k) {
        const float4 x = *reinterpret_cast<const float4*>(&xs[k * 16 + nt * 4]);
        const float4 w = *reinterpret_cast<const float4*>(&Wp0[k * 192 + j0]);
        const float wr[4] = { w.x, w.y, w.z, w.w };
        const float xr[4] = { x.x, x.y, x.z, x.w };
        #pragma unroll
        for (int r = 0; r < 4; ++r)
            #pragma unroll
            for (int n = 0; n < 4; ++n) a0[r][n] += wr[r] * xr[n];
    }
    #pragma unroll 2
    for (int k = 0; k < 84; ++k) {
        const float4 x = *reinterpret_cast<const float4*>(&xs[(300 + k) * 16 + nt * 4]);
        const float4 w = *reinterpret_cast<const float4*>(&Wp1[k * 192 + j0]);
        const float wr[4] = { w.x, w.y, w.z, w.w };
        const float xr[4] = { x.x, x.y, x.z, x.w };
        #pragma unroll
        for (int r = 0; r < 4; ++r)
            #pragma unroll
            for (int n = 0; n < 4; ++n) a1[r][n] += wr[r] * xr[n];
    }
    {
        const float4 b0 = *reinterpret_cast<const float4*>(&bp0[j0]);
        const float4 b1 = *reinterpret_cast<const float4*>(&bp1[j0]);
        const float b0r[4] = { b0.x, b0.y, b0.z, b0.w };
        const float b1r[4] = { b1.x, b1.y, b1.z, b1.w };
        #pragma unroll
        for (int r = 0; r < 4; ++r)
            #pragma unroll
            for (int n = 0; n < 4; ++n) { a0[r][n] += b0r[r]; a1[r][n] += b1r[r]; }
    }
    __syncthreads();
    float2* red = (float2*)xs;

    #pragma unroll
    for (int n = 0; n < 4; ++n) {
        float s = 0.f, q = 0.f;
        #pragma unroll
        for (int r = 0; r < 4; ++r) { s += a0[r][n]; q += a0[r][n] * a0[r][n]; }
        red[jg * 16 + nt * 4 + n] = make_float2(s, q);
    }
    __syncthreads();
    if (tid < 16) {
        float s = 0.f, q = 0.f;
        for (int g = 0; g < 48; ++g) { float2 v = red[g * 16 + tid]; s += v.x; q += v.y; }
        float mu = s * (1.f / 192.f);
        float var = q * (1.f / 192.f) - mu * mu;
        stats0[tid] = make_float2(mu, rsqrtf(var + 1e-5f));
    }
    __syncthreads();
    #pragma unroll
    for (int n = 0; n < 4; ++n) {
        float s = 0.f, q = 0.f;
        #pragma unroll
        for (int r = 0; r < 4; ++r) { s += a1[r][n]; q += a1[r][n] * a1[r][n]; }
        red[jg * 16 + nt * 4 + n] = make_float2(s, q);
    }
    {
        const float4 g = *reinterpret_cast<const float4*>(&gp0[j0]);
        const float4 be = *reinterpret_cast<const float4*>(&bep0[j0]);
        const float gr[4] = { g.x, g.y, g.z, g.w };
        const float br[4] = { be.x, be.y, be.z, be.w };
        #pragma unroll
        for (int n = 0; n < 4; ++n) {
            float2 st = stats0[nt * 4 + n];
            float4 o;
            o.x = fmaxf((a0[0][n] - st.x) * st.y * gr[0] + br[0], 0.f);
            o.y = fmaxf((a0[1][n] - st.x) * st.y * gr[1] + br[1], 0.f);
            o.z = fmaxf((a0[2][n] - st.x) * st.y * gr[2] + br[2], 0.f);
            o.w = fmaxf((a0[3][n] - st.x) * st.y * gr[3] + br[3], 0.f);
            *reinterpret_cast<float4*>(&hp[(size_t)(n0 + nt * 4 + n) * 384 + j0]) = o;
        }
    }
    __syncthreads();
    if (tid < 16) {
        float s = 0.f, q = 0.f;
        for (int g = 0; g < 48; ++g) { float2 v = red[g * 16 + tid]; s += v.x; q += v.y; }
        float mu = s * (1.f / 192.f);
        float var = q * (1.f / 192.f) - mu * mu;
        stats1[tid] = make_float2(mu, rsqrtf(var + 1e-5f));
    }
    __syncthreads();
    {
        const float4 g = *reinterpret_cast<const float4*>(&gp1[j0]);
        const float4 be = *reinterpret_cast<const float4*>(&bep1[j0]);
        const float gr[4] = { g.x, g.y, g.z, g.w };
        const float br[4] = { be.x, be.y, be.z, be.w };
        #pragma unroll
        for (int n = 0; n < 4; ++n) {
            float2 st = stats1[nt * 4 + n];
            float4 o;
            o.x = fmaxf((a1[0][n] - st.x) * st.y * gr[0] + br[0], 0.f);
            o.y = fmaxf((a1[1][n] - st.x) * st.y * gr[1] + br[1], 0.f);
            o.z = fmaxf((a1[2][n] - st.x) * st.y * gr[2] + br[2], 0.f);
            o.w = fmaxf((a1[3][n] - st.x) * st.y * gr[3] + br[3], 0.f);
            *reinterpret_cast<float4*>(&hp[(size_t)(n0 + nt * 4 + n) * 384 + 192 + j0]) = o;
        }
    }
}

// ---------------------------------------------------------------------------
// Kernel B: edge scatter (unchanged).
// ---------------------------------------------------------------------------
__global__ __launch_bounds__(256) void k_scatter(
    const float* __restrict__ hp,
    const int* __restrict__ src, const int* __restrict__ dst,
    const int* __restrict__ pos, const float* __restrict__ dist,
    float* __restrict__ acc)
{
    int gid = blockIdx.x * 256 + threadIdx.x;   // NE*96 total
    int e  = gid / 96;
    int f4 = (gid - e * 96) * 4;
    int p = pos[e];
    if (p >= 3) return;
    float w = dist[e];
    int s = src[e], d = dst[e];
    const float4 v = *reinterpret_cast<const float4*>(&hp[(size_t)s * 384 + f4]);
    float* o = &acc[(size_t)d * 1152 + (size_t)p * 384 + f4];
    atomicAdd(o + 0, v.x * w);
    atomicAdd(o + 1, v.y * w);
    atomicAdd(o + 2, v.z * w);
    atomicAdd(o + 3, v.w * w);
}

// ---------------------------------------------------------------------------
// Kernel C: hg = relu(LN(hc @ Wg + bg)) (unchanged from R6).
// ---------------------------------------------------------------------------
__global__ __launch_bounds__(256) void k_gemm_hg(
    const float* __restrict__ hp, const float* __restrict__ acc,
    const float* __restrict__ Wg, const float* __restrict__ bg,
    const float* __restrict__ gg, const float* __restrict__ beg,
    float* __restrict__ hg)
{
    __shared__ __align__(16) float xs[384 * 32];    // [c][n], 48 KB
    const int tid = threadIdx.x;
    const int n0  = blockIdx.x * 32;
    const int jg  = tid & 31;           // 32 groups * 12 j = 384
    const int nt  = tid >> 5;           // 8 groups * 4 nodes = 32
    const int j0  = jg * 12;
    const int nb  = nt * 4;
    const int ns  = tid & 31;           // staging: fixed node per thread

    float a[12][4];
    #pragma unroll
    for (int r = 0; r < 12; ++r)
        #pragma unroll
        for (int n = 0; n < 4; ++n) a[r][n] = 0.f;

    for (int t = 0; t < 5; ++t) {
        const float* srow;
        if (t == 0)      srow = hp  + (size_t)(n0 + ns) * 384;
        else if (t < 4)  srow = acc + (size_t)(n0 + ns) * 1152 + (size_t)(t - 1) * 384;
        else             srow = acc + (size_t)(n0 + ns) * 1152;           // t = r
        for (int c = tid >> 5; c < 384; c += 8)
            xs[c * 32 + ns] = srow[c];
        __syncthreads();

        const float* wp = Wg + (size_t)t * 384 * 384 + j0;
        for (int kl = 0; kl < 384; ++kl) {
            const float4 w0 = *reinterpret_cast<const float4*>(wp + 0);
            const float4 w1 = *reinterpret_cast<const float4*>(wp + 4);
            const float4 w2 = *reinterpret_cast<const float4*>(wp + 8);
            wp += 384;
            const float4 x = *reinterpret_cast<const float4*>(&xs[kl * 32 + nb]);
            const float wr[12] = { w0.x, w0.y, w0.z, w0.w, w1.x, w1.y, w1.z, w1.w,
                                   w2.x, w2.y, w2.z, w2.w };
            const float xr[4]  = { x.x, x.y, x.z, x.w };
            #pragma unroll
            for (int r = 0; r < 12; ++r)
                #pragma unroll
                for (int n = 0; n < 4; ++n) a[r][n] += wr[r] * xr[n];
        }
        __syncthreads();
    }
    {
        const float4 b0 = *reinterpret_cast<const float4*>(&bg[j0 + 0]);
        const float4 b1 = *reinterpret_cast<const float4*>(&bg[j0 + 4]);
        const float4 b2 = *reinterpret_cast<const float4*>(&bg[j0 + 8]);
        const float br[12] = { b0.x, b0.y, b0.z, b0.w, b1.x, b1.y, b1.z, b1.w,
                               b2.x, b2.y, b2.z, b2.w };
        #pragma unroll
        for (int r = 0; r < 12; ++r)
            #pragma unroll
            for (int n = 0; n < 4; ++n) a[r][n] += br[r];
    }
    const float4 gA = *reinterpret_cast<const float4*>(&gg[j0 + 0]);
    const float4 gB = *reinterpret_cast<const float4*>(&gg[j0 + 4]);
    const float4 gC = *reinterpret_cast<const float4*>(&gg[j0 + 8]);
    const float4 eA = *reinterpret_cast<const float4*>(&beg[j0 + 0]);
    const float4 eB = *reinterpret_cast<const float4*>(&beg[j0 + 4]);
    const float4 eC = *reinterpret_cast<const float4*>(&beg[j0 + 8]);
    const float gr[12] = { gA.x, gA.y, gA.z, gA.w, gB.x, gB.y, gB.z, gB.w,
                           gC.x, gC.y, gC.z, gC.w };
    const float er[12] = { eA.x, eA.y, eA.z, eA.w, eB.x, eB.y, eB.z, eB.w,
                           eC.x, eC.y, eC.z, eC.w };
    #pragma unroll
    for (int n = 0; n < 4; ++n) {
        float s = 0.f, q = 0.f;
        #pragma unroll
        for (int r = 0; r < 12; ++r) { s += a[r][n]; q += a[r][n] * a[r][n]; }
        #pragma unroll
        for (int o = 16; o > 0; o >>= 1) {
            s += __shfl_xor(s, o, 32);
            q += __shfl_xor(q, o, 32);
        }
        float mu = s * (1.f / 384.f);
        float var = q * (1.f / 384.f) - mu * mu;
        float rs = rsqrtf(var + 1e-5f);
        float out[12];
        #pragma unroll
        for (int r = 0; r < 12; ++r)
            out[r] = fmaxf((a[r][n] - mu) * rs * gr[r] + er[r], 0.f);
        float* orow = &hg[(size_t)(n0 + nb + n) * 384 + j0];
        *reinterpret_cast<float4*>(orow + 0) = make_float4(out[0], out[1], out[2], out[3]);
        *reinterpret_cast<float4*>(orow + 4) = make_float4(out[4], out[5], out[6], out[7]);
        *reinterpret_cast<float4*>(orow + 8) = make_float4(out[8], out[9], out[10], out[11]);
    }
}

// ---------------------------------------------------------------------------
// Kernel D: n = LN(hg @ Wn + bn); cls = softmax(n).  1 wave / node.
// ---------------------------------------------------------------------------
__global__ __launch_bounds__(256) void k_node_head(
    const float* __restrict__ hg,
    const float* __restrict__ Wn, const float* __restrict__ bn,
    const float* __restrict__ gn, const float* __restrict__ ben,
    float* __restrict__ nout, float* __restrict__ cls)
{
    __shared__ float wns[384 * 5];
    const int tid = threadIdx.x;
    for (int i = tid; i < 1920; i += 256) wns[i] = Wn[i];
    __syncthreads();
    const int wid = tid >> 6, lane = tid & 63;
    const int node = blockIdx.x * 4 + wid;
    float a0 = 0, a1 = 0, a2 = 0, a3 = 0, a4 = 0;
    const float* row = hg + (size_t)node * 384;
    for (int k = lane; k < 384; k += 64) {
        float v = row[k];
        const float* wp = &wns[k * 5];
        a0 += v * wp[0]; a1 += v * wp[1]; a2 += v * wp[2];
        a3 += v * wp[3]; a4 += v * wp[4];
    }
    for (int o = 32; o > 0; o >>= 1) {
        a0 += __shfl_down(a0, o); a1 += __shfl_down(a1, o);
        a2 += __shfl_down(a2, o); a3 += __shfl_down(a3, o);
        a4 += __shfl_down(a4, o);
    }
    if (lane == 0) {
        float v[5] = { a0 + bn[0], a1 + bn[1], a2 + bn[2], a3 + bn[3], a4 + bn[4] };
        float mu = (v[0] + v[1] + v[2] + v[3] + v[4]) * 0.2f;
        float var = 0.0f;
        #pragma unroll
        for (int c = 0; c < 5; ++c) { float d = v[c] - mu; var += d * d; }
        var *= 0.2f;
        float rs = rsqrtf(var + 1e-5f);
        float nv[5]; float m = -1e30f;
        #pragma unroll
        for (int c = 0; c < 5; ++c) {
            nv[c] = (v[c] - mu) * rs * gn[c] + ben[c];
            m = fmaxf(m, nv[c]);
        }
        #pragma unroll
        for (int c = 0; c < 5; ++c) nout[(size_t)node * 5 + c] = nv[c];
        float ex[5]; float s = 0.0f;
        #pragma unroll
        for (int c = 0; c < 5; ++c) { ex[c] = expf(nv[c] - m); s += ex[c]; }
        float inv = 1.0f / s;
        #pragma unroll
        for (int c = 0; c < 5; ++c) cls[(size_t)node * 5 + c] = ex[c] * inv;
    }
}

// ---------------------------------------------------------------------------
// Kernel E: edge MLP, small register tile (spill-free).
// 32 edges/block (8000 blocks), 256 threads = 8 half-waves.
// Half-wave hw = tid>>5 owns 4 edges (eb = hw*4); jg = tid&31 owns
// j = jg*10..+9 (Jr=10; jg<30 active).  acc = 40 VGPR, live ~75 ->
// no spill at <=128 VGPR (occupancy plateau 65..128 = 16 waves/CU).
// LDS tile xs[e][cl] stride 200, KC=196, 4 phases, 25.6 KB.
// Staging: lanes = consecutive c of one edge row -> coalesced global +
// conflict-free LDS writes.  Compute reads broadcast (2 addrs/wave = free).
// LN + W2 epilogue in-register via __shfl_xor width-32.
// ---------------------------------------------------------------------------
#define EM_KC 196
#define EM_ST 200

__global__ __launch_bounds__(256, 2) void k_edge_mlp(
    const float* __restrict__ hg, const float* __restrict__ cls,
    const int* __restrict__ srcI, const int* __restrict__ dstI,
    const float* __restrict__ polar,
    const float* __restrict__ W1, const float* __restrict__ b1,
    const float* __restrict__ g1, const float* __restrict__ be1,
    const float* __restrict__ W2, const float* __restrict__ b2,
    float* __restrict__ eout)
{
    __shared__ __align__(16) float xs[32 * EM_ST];   // [e][cl], 25.6 KB
    const int tid = threadIdx.x;
    const int e0  = blockIdx.x * 32;
    const int hw  = tid >> 5;            // half-wave id, 0..7
    const int jg  = tid & 31;            // 0..31, active jg<30
    const bool act = (jg < 30);
    const float actf = act ? 1.f : 0.f;
    const int j0  = (act ? jg : 29) * 10;
    const int eb  = hw * 4;

    // staging identity: 4 e-groups x 64 c-lanes
    const int c_sel = tid & 63;
    const int e_grp = tid >> 6;          // 0..3, 8 edges each

    float a[10][4];                      // [j][e]
    #pragma unroll
    for (int r = 0; r < 10; ++r)
        #pragma unroll
        for (int e = 0; e < 4; ++e) a[r][e] = 0.f;

    for (int t = 0; t < 4; ++t) {
        // ---- stage x[e][cl]: lanes = consecutive c -> coalesced global,
        //      conflict-free LDS writes ----
        for (int eo = 0; eo < 8; ++eo) {
            const int e  = e_grp * 8 + eo;
            const int eg = e0 + e;
            const int se = srcI[eg], de = dstI[eg];
            for (int c = c_sel; c < EM_KC; c += 64) {
                const int cg = t * EM_KC + c;
                float v;
                if (cg < 384)      v = hg[(size_t)se * 384 + cg];
                else if (cg < 389) v = cls[(size_t)se * 5 + (cg - 384)];
                else if (cg < 395) v = polar[(size_t)eg * 6 + (cg - 389)];
                else if (cg < 779) v = hg[(size_t)de * 384 + (cg - 395)];
                else               v = cls[(size_t)de * 5 + (cg - 779)];
                xs[e * EM_ST + c] = v;
            }
        }
        __syncthreads();

        const float* wbase = W1 + (size_t)(t * EM_KC) * 300 + j0;
        for (int kq = 0; kq < EM_KC / 2; ++kq) {
            float2 xv[4];
            #pragma unroll
            for (int i = 0; i < 4; ++i)
                xv[i] = *reinterpret_cast<const float2*>(&xs[(eb + i) * EM_ST + kq * 2]);
            const float* wp = wbase + (size_t)(kq * 2) * 300;
            #pragma unroll
            for (int kk = 0; kk < 2; ++kk) {
                const float2 wA = *reinterpret_cast<const float2*>(wp + kk * 300 + 0);
                const float2 wB = *reinterpret_cast<const float2*>(wp + kk * 300 + 2);
                const float2 wC = *reinterpret_cast<const float2*>(wp + kk * 300 + 4);
                const float2 wD = *reinterpret_cast<const float2*>(wp + kk * 300 + 6);
                const float2 wE = *reinterpret_cast<const float2*>(wp + kk * 300 + 8);
                const float wr[10] = { wA.x, wA.y, wB.x, wB.y, wC.x, wC.y,
                                       wD.x, wD.y, wE.x, wE.y };
                const float xk[4] = {
                    kk ? xv[0].y : xv[0].x, kk ? xv[1].y : xv[1].x,
                    kk ? xv[2].y : xv[2].x, kk ? xv[3].y : xv[3].x };
                #pragma unroll
                for (int r = 0; r < 10; ++r)
                    #pragma unroll
                    for (int e = 0; e < 4; ++e) a[r][e] += wr[r] * xk[e];
            }
        }
        __syncthreads();
    }

    // ---- bias ----
    {
        const float2 bA = *reinterpret_cast<const float2*>(&b1[j0 + 0]);
        const float2 bB = *reinterpret_cast<const float2*>(&b1[j0 + 2]);
        const float2 bC = *reinterpret_cast<const float2*>(&b1[j0 + 4]);
        const float2 bD = *reinterpret_cast<const float2*>(&b1[j0 + 6]);
        const float2 bE = *reinterpret_cast<const float2*>(&b1[j0 + 8]);
        const float br[10] = { bA.x, bA.y, bB.x, bB.y, bC.x, bC.y,
                               bD.x, bD.y, bE.x, bE.y };
        #pragma unroll
        for (int r = 0; r < 10; ++r)
            #pragma unroll
            for (int e = 0; e < 4; ++e) a[r][e] += br[r];
    }

    // ---- LN stats: butterfly over the 32-lane jg dimension ----
    float mu[4], rs[4];
    #pragma unroll
    for (int e = 0; e < 4; ++e) {
        float s = 0.f, q = 0.f;
        #pragma unroll
        for (int r = 0; r < 10; ++r) { s += a[r][e]; q += a[r][e] * a[r][e]; }
        s *= actf; q *= actf;
        #pragma unroll
        for (int o = 16; o > 0; o >>= 1) {
            s += __shfl_xor(s, o, 32);
            q += __shfl_xor(q, o, 32);
        }
        mu[e] = s * (1.f / 300.f);
        float var = q * (1.f / 300.f) - mu[e] * mu[e];
        rs[e] = rsqrtf(var + 1e-5f);
    }

    // ---- LN + relu + layer-2 partials + butterfly reduce ----
    const float2 gA = *reinterpret_cast<const float2*>(&g1[j0 + 0]);
    const float2 gB = *reinterpret_cast<const float2*>(&g1[j0 + 2]);
    const float2 gC = *reinterpret_cast<const float2*>(&g1[j0 + 4]);
    const float2 gD = *reinterpret_cast<const float2*>(&g1[j0 + 6]);
    const float2 gE = *reinterpret_cast<const float2*>(&g1[j0 + 8]);
    const float2 eA = *reinterpret_cast<const float2*>(&be1[j0 + 0]);
    const float2 eB = *reinterpret_cast<const float2*>(&be1[j0 + 2]);
    const float2 eC = *reinterpret_cast<const float2*>(&be1[j0 + 4]);
    const float2 eD = *reinterpret_cast<const float2*>(&be1[j0 + 6]);
    const float2 eE = *reinterpret_cast<const float2*>(&be1[j0 + 8]);
    const float gr[10] = { gA.x, gA.y, gB.x, gB.y, gC.x, gC.y, gD.x, gD.y, gE.x, gE.y };
    const float er[10] = { eA.x, eA.y, eB.x, eB.y, eC.x, eC.y, eD.x, eD.y, eE.x, eE.y };
    float w20[10], w21[10];
    #pragma unroll
    for (int r = 0; r < 10; ++r) {
        const float2 w2 = *reinterpret_cast<const float2*>(&W2[(j0 + r) * 2]);
        w20[r] = w2.x; w21[r] = w2.y;
    }
    float o0[4], o1[4];
    #pragma unroll
    for (int e = 0; e < 4; ++e) {
        float s0 = 0.f, s1 = 0.f;
        #pragma unroll
        for (int r = 0; r < 10; ++r) {
            float y = fmaxf((a[r][e] - mu[e]) * rs[e] * gr[r] + er[r], 0.f);
            s0 += y * w20[r];
            s1 += y * w21[r];
        }
        s0 *= actf; s1 *= actf;
        #pragma unroll
        for (int o = 16; o > 0; o >>= 1) {
            s0 += __shfl_xor(s0, o, 32);
            s1 += __shfl_xor(s1, o, 32);
        }
        o0[e] = s0; o1[e] = s1;
    }
    if (jg == 0) {
        const float b20 = b2[0], b21 = b2[1];
        #pragma unroll
        for (int e = 0; e < 4; ++e)
            *reinterpret_cast<float2*>(&eout[(size_t)(e0 + eb + e) * 2]) =
                make_float2(o0[e] + b20, o1[e] + b21);
    }
}

// ---------------------------------------------------------------------------
extern "C" void kernel_launch(void* const* d_in, const int* in_sizes, int n_in,
                              void* d_out, int out_size, void* d_ws, size_t ws_size,
                              hipStream_t stream)
{
    const float* h     = (const float*)d_in[0];
    const int*   src   = (const int*)d_in[1];
    const int*   dst   = (const int*)d_in[2];
    const int*   pos   = (const int*)d_in[3];
    const float* dist  = (const float*)d_in[4];
    const float* polar = (const float*)d_in[5];
    const float* Wp0   = (const float*)d_in[6];
    const float* bp0   = (const float*)d_in[7];
    const float* gp0   = (const float*)d_in[8];
    const float* bep0  = (const float*)d_in[9];
    const float* Wp1   = (const float*)d_in[10];
    const float* bp1   = (const float*)d_in[11];
    const float* gp1   = (const float*)d_in[12];
    const float* bep1  = (const float*)d_in[13];
    const float* Wg    = (const float*)d_in[14];
    const float* bg    = (const float*)d_in[15];
    const float* gg    = (const float*)d_in[16];
    const float* beg   = (const float*)d_in[17];
    const float* Wn    = (const float*)d_in[18];
    const float* bn    = (const float*)d_in[19];
    const float* gn    = (const float*)d_in[20];
    const float* ben   = (const float*)d_in[21];
    const float* W1    = (const float*)d_in[22];
    const float* b1    = (const float*)d_in[23];
    const float* g1    = (const float*)d_in[24];
    const float* be1   = (const float*)d_in[25];
    const float* W2    = (const float*)d_in[26];
    const float* b2    = (const float*)d_in[27];

    float* ws  = (float*)d_ws;
    float* acc = ws + ACC_OFF;
    float* hp  = ws + HP_OFF;
    float* hg  = hp;                        // aliased (see k_gemm_hg comment)
    float* cls = ws + CLS_OFF;
    float* nout = (float*)d_out;            // 40000*5
    float* eout = (float*)d_out + 200000;   // 256000*2

    k_zero<<<2048, 256, 0, stream>>>((float4*)acc, ACC_FLOATS / 4);

    k_proj<<<2500, 192, 0, stream>>>(h, Wp0, bp0, gp0, bep0,
                                     Wp1, bp1, gp1, bep1, hp);
    k_scatter<<<96000, 256, 0, stream>>>(hp, src, dst, pos, dist, acc);
    k_gemm_hg<<<1250, 256, 0, stream>>>(hp, acc, Wg, bg, gg, beg, hg);
    k_node_head<<<10000, 256, 0, stream>>>(hg, Wn, bn, gn, ben, nout, cls);
    k_edge_mlp<<<8000, 256, 0, stream>>>(hg, cls, src, dst, polar,
                                         W1, b1, g1, be1, W2, b2, eout);
}

// Round 9
// 4631.737 us; speedup vs baseline: 1.3185x; 1.3185x over previous
//
#include <hip/hip_runtime.h>
#include <math.h>

// Problem constants
#define NN 40000
#define NE 256000

// Workspace layout (floats), total 61,640,000 floats = 246.6 MB
//  acc : 40000*1152 = 46,080,000   [r|b|l] scatter accumulators
//  hp  : 40000*384  = 15,360,000   projected node features; REUSED as hg
//  cls : 40000*5    =    200,000   softmax probs
static const size_t ACC_OFF = 0;
static const size_t HP_OFF  = 46080000;
static const size_t CLS_OFF = 61440000;
#define ACC_FLOATS 46080000

// ---------------------------------------------------------------------------
__global__ __launch_bounds__(256) void k_zero(float4* __restrict__ p, int n4)
{
    int stride = gridDim.x * 256;
    for (int i = blockIdx.x * 256 + threadIdx.x; i < n4; i += stride)
        p[i] = make_float4(0.f, 0.f, 0.f, 0.f);
}

// ---------------------------------------------------------------------------
// Kernel A: fused projections, register-blocked (unchanged).
// ---------------------------------------------------------------------------
__global__ __launch_bounds__(192) void k_proj(
    const float* __restrict__ h,
    const float* __restrict__ Wp0, const float* __restrict__ bp0,
    const float* __restrict__ gp0, const float* __restrict__ bep0,
    const float* __restrict__ Wp1, const float* __restrict__ bp1,
    const float* __restrict__ gp1, const float* __restrict__ bep1,
    float* __restrict__ hp)
{
    __shared__ __align__(16) float xs[384 * 16];   // [c][n], 24.6 KB
    __shared__ float2 stats0[16], stats1[16];
    const int tid = threadIdx.x;
    const int n0  = blockIdx.x * 16;
    const int jg  = tid % 48;
    const int nt  = tid / 48;
    const int j0  = jg * 4;

    for (int idx = tid; idx < 384 * 16; idx += 192) {
        int n = idx & 15, c = idx >> 4;
        xs[c * 16 + n] = h[(size_t)(n0 + n) * 384 + c];
    }
    __syncthreads();

    float a0[4][4], a1[4][4];
    #pragma unroll
    for (int r = 0; r < 4; ++r)
        #pragma unroll
        for (int n = 0; n < 4; ++n) { a0[r][n] = 0.f; a1[r][n] = 0.f; }

    #pragma unroll 2
    for (int k = 0; k < 300; ++k) {
        const float4 x = *reinterpret_cast<const float4*>(&xs[k * 16 + nt * 4]);
        const float4 w = *reinterpret_cast<const float4*>(&Wp0[k * 192 + j0]);
        const float wr[4] = { w.x, w.y, w.z, w.w };
        const float xr[4] = { x.x, x.y, x.z, x.w };
        #pragma unroll
        for (int r = 0; r < 4; ++r)
            #pragma unroll
            for (int n = 0; n < 4; ++n) a0[r][n] += wr[r] * xr[n];
    }
    #pragma unroll 2
    for (int k = 0; k < 84; ++k) {
        const float4 x = *reinterpret_cast<const float4*>(&xs[(300 + k) * 16 + nt * 4]);
        const float4 w = *reinterpret_cast<const float4*>(&Wp1[k * 192 + j0]);
        const float wr[4] = { w.x, w.y, w.z, w.w };
        const float xr[4] = { x.x, x.y, x.z, x.w };
        #pragma unroll
        for (int r = 0; r < 4; ++r)
            #pragma unroll
            for (int n = 0; n < 4; ++n) a1[r][n] += wr[r] * xr[n];
    }
    {
        const float4 b0 = *reinterpret_cast<const float4*>(&bp0[j0]);
        const float4 b1 = *reinterpret_cast<const float4*>(&bp1[j0]);
        const float b0r[4] = { b0.x, b0.y, b0.z, b0.w };
        const float b1r[4] = { b1.x, b1.y, b1.z, b1.w };
        #pragma unroll
        for (int r = 0; r < 4; ++r)
            #pragma unroll
            for (int n = 0; n < 4; ++n) { a0[r][n] += b0r[r]; a1[r][n] += b1r[r]; }
    }
    __syncthreads();
    float2* red = (float2*)xs;

    #pragma unroll
    for (int n = 0; n < 4; ++n) {
        float s = 0.f, q = 0.f;
        #pragma unroll
        for (int r = 0; r < 4; ++r) { s += a0[r][n]; q += a0[r][n] * a0[r][n]; }
        red[jg * 16 + nt * 4 + n] = make_float2(s, q);
    }
    __syncthreads();
    if (tid < 16) {
        float s = 0.f, q = 0.f;
        for (int g = 0; g < 48; ++g) { float2 v = red[g * 16 + tid]; s += v.x; q += v.y; }
        float mu = s * (1.f / 192.f);
        float var = q * (1.f / 192.f) - mu * mu;
        stats0[tid] = make_float2(mu, rsqrtf(var + 1e-5f));
    }
    __syncthreads();
    #pragma unroll
    for (int n = 0; n < 4; ++n) {
        float s = 0.f, q = 0.f;
        #pragma unroll
        for (int r = 0; r < 4; ++r) { s += a1[r][n]; q += a1[r][n] * a1[r][n]; }
        red[jg * 16 + nt * 4 + n] = make_float2(s, q);
    }
    {
        const float4 g = *reinterpret_cast<const float4*>(&gp0[j0]);
        const float4 be = *reinterpret_cast<const float4*>(&bep0[j0]);
        const float gr[4] = { g.x, g.y, g.z, g.w };
        const float br[4] = { be.x, be.y, be.z, be.w };
        #pragma unroll
        for (int n = 0; n < 4; ++n) {
            float2 st = stats0[nt * 4 + n];
            float4 o;
            o.x = fmaxf((a0[0][n] - st.x) * st.y * gr[0] + br[0], 0.f);
            o.y = fmaxf((a0[1][n] - st.x) * st.y * gr[1] + br[1], 0.f);
            o.z = fmaxf((a0[2][n] - st.x) * st.y * gr[2] + br[2], 0.f);
            o.w = fmaxf((a0[3][n] - st.x) * st.y * gr[3] + br[3], 0.f);
            *reinterpret_cast<float4*>(&hp[(size_t)(n0 + nt * 4 + n) * 384 + j0]) = o;
        }
    }
    __syncthreads();
    if (tid < 16) {
        float s = 0.f, q = 0.f;
        for (int g = 0; g < 48; ++g) { float2 v = red[g * 16 + tid]; s += v.x; q += v.y; }
        float mu = s * (1.f / 192.f);
        float var = q * (1.f / 192.f) - mu * mu;
        stats1[tid] = make_float2(mu, rsqrtf(var + 1e-5f));
    }
    __syncthreads();
    {
        const float4 g = *reinterpret_cast<const float4*>(&gp1[j0]);
        const float4 be = *reinterpret_cast<const float4*>(&bep1[j0]);
        const float gr[4] = { g.x, g.y, g.z, g.w };
        const float br[4] = { be.x, be.y, be.z, be.w };
        #pragma unroll
        for (int n = 0; n < 4; ++n) {
            float2 st = stats1[nt * 4 + n];
            float4 o;
            o.x = fmaxf((a1[0][n] - st.x) * st.y * gr[0] + br[0], 0.f);
            o.y = fmaxf((a1[1][n] - st.x) * st.y * gr[1] + br[1], 0.f);
            o.z = fmaxf((a1[2][n] - st.x) * st.y * gr[2] + br[2], 0.f);
            o.w = fmaxf((a1[3][n] - st.x) * st.y * gr[3] + br[3], 0.f);
            *reinterpret_cast<float4*>(&hp[(size_t)(n0 + nt * 4 + n) * 384 + 192 + j0]) = o;
        }
    }
}

// ---------------------------------------------------------------------------
// Kernel B: edge scatter (unchanged).
// ---------------------------------------------------------------------------
__global__ __launch_bounds__(256) void k_scatter(
    const float* __restrict__ hp,
    const int* __restrict__ src, const int* __restrict__ dst,
    const int* __restrict__ pos, const float* __restrict__ dist,
    float* __restrict__ acc)
{
    int gid = blockIdx.x * 256 + threadIdx.x;   // NE*96 total
    int e  = gid / 96;
    int f4 = (gid - e * 96) * 4;
    int p = pos[e];
    if (p >= 3) return;
    float w = dist[e];
    int s = src[e], d = dst[e];
    const float4 v = *reinterpret_cast<const float4*>(&hp[(size_t)s * 384 + f4]);
    float* o = &acc[(size_t)d * 1152 + (size_t)p * 384 + f4];
    atomicAdd(o + 0, v.x * w);
    atomicAdd(o + 1, v.y * w);
    atomicAdd(o + 2, v.z * w);
    atomicAdd(o + 3, v.w * w);
}

// ---------------------------------------------------------------------------
// Kernel C: hg = relu(LN(hc @ Wg + bg)) (unchanged from R6).
// ---------------------------------------------------------------------------
__global__ __launch_bounds__(256) void k_gemm_hg(
    const float* __restrict__ hp, const float* __restrict__ acc,
    const float* __restrict__ Wg, const float* __restrict__ bg,
    const float* __restrict__ gg, const float* __restrict__ beg,
    float* __restrict__ hg)
{
    __shared__ __align__(16) float xs[384 * 32];    // [c][n], 48 KB
    const int tid = threadIdx.x;
    const int n0  = blockIdx.x * 32;
    const int jg  = tid & 31;           // 32 groups * 12 j = 384
    const int nt  = tid >> 5;           // 8 groups * 4 nodes = 32
    const int j0  = jg * 12;
    const int nb  = nt * 4;
    const int ns  = tid & 31;           // staging: fixed node per thread

    float a[12][4];
    #pragma unroll
    for (int r = 0; r < 12; ++r)
        #pragma unroll
        for (int n = 0; n < 4; ++n) a[r][n] = 0.f;

    for (int t = 0; t < 5; ++t) {
        const float* srow;
        if (t == 0)      srow = hp  + (size_t)(n0 + ns) * 384;
        else if (t < 4)  srow = acc + (size_t)(n0 + ns) * 1152 + (size_t)(t - 1) * 384;
        else             srow = acc + (size_t)(n0 + ns) * 1152;           // t = r
        for (int c = tid >> 5; c < 384; c += 8)
            xs[c * 32 + ns] = srow[c];
        __syncthreads();

        const float* wp = Wg + (size_t)t * 384 * 384 + j0;
        for (int kl = 0; kl < 384; ++kl) {
            const float4 w0 = *reinterpret_cast<const float4*>(wp + 0);
            const float4 w1 = *reinterpret_cast<const float4*>(wp + 4);
            const float4 w2 = *reinterpret_cast<const float4*>(wp + 8);
            wp += 384;
            const float4 x = *reinterpret_cast<const float4*>(&xs[kl * 32 + nb]);
            const float wr[12] = { w0.x, w0.y, w0.z, w0.w, w1.x, w1.y, w1.z, w1.w,
                                   w2.x, w2.y, w2.z, w2.w };
            const float xr[4]  = { x.x, x.y, x.z, x.w };
            #pragma unroll
            for (int r = 0; r < 12; ++r)
                #pragma unroll
                for (int n = 0; n < 4; ++n) a[r][n] += wr[r] * xr[n];
        }
        __syncthreads();
    }
    {
        const float4 b0 = *reinterpret_cast<const float4*>(&bg[j0 + 0]);
        const float4 b1 = *reinterpret_cast<const float4*>(&bg[j0 + 4]);
        const float4 b2 = *reinterpret_cast<const float4*>(&bg[j0 + 8]);
        const float br[12] = { b0.x, b0.y, b0.z, b0.w, b1.x, b1.y, b1.z, b1.w,
                               b2.x, b2.y, b2.z, b2.w };
        #pragma unroll
        for (int r = 0; r < 12; ++r)
            #pragma unroll
            for (int n = 0; n < 4; ++n) a[r][n] += br[r];
    }
    const float4 gA = *reinterpret_cast<const float4*>(&gg[j0 + 0]);
    const float4 gB = *reinterpret_cast<const float4*>(&gg[j0 + 4]);
    const float4 gC = *reinterpret_cast<const float4*>(&gg[j0 + 8]);
    const float4 eA = *reinterpret_cast<const float4*>(&beg[j0 + 0]);
    const float4 eB = *reinterpret_cast<const float4*>(&beg[j0 + 4]);
    const float4 eC = *reinterpret_cast<const float4*>(&beg[j0 + 8]);
    const float gr[12] = { gA.x, gA.y, gA.z, gA.w, gB.x, gB.y, gB.z, gB.w,
                           gC.x, gC.y, gC.z, gC.w };
    const float er[12] = { eA.x, eA.y, eA.z, eA.w, eB.x, eB.y, eB.z, eB.w,
                           eC.x, eC.y, eC.z, eC.w };
    #pragma unroll
    for (int n = 0; n < 4; ++n) {
        float s = 0.f, q = 0.f;
        #pragma unroll
        for (int r = 0; r < 12; ++r) { s += a[r][n]; q += a[r][n] * a[r][n]; }
        #pragma unroll
        for (int o = 16; o > 0; o >>= 1) {
            s += __shfl_xor(s, o, 32);
            q += __shfl_xor(q, o, 32);
        }
        float mu = s * (1.f / 384.f);
        float var = q * (1.f / 384.f) - mu * mu;
        float rs = rsqrtf(var + 1e-5f);
        float out[12];
        #pragma unroll
        for (int r = 0; r < 12; ++r)
            out[r] = fmaxf((a[r][n] - mu) * rs * gr[r] + er[r], 0.f);
        float* orow = &hg[(size_t)(n0 + nb + n) * 384 + j0];
        *reinterpret_cast<float4*>(orow + 0) = make_float4(out[0], out[1], out[2], out[3]);
        *reinterpret_cast<float4*>(orow + 4) = make_float4(out[4], out[5], out[6], out[7]);
        *reinterpret_cast<float4*>(orow + 8) = make_float4(out[8], out[9], out[10], out[11]);
    }
}

// ---------------------------------------------------------------------------
// Kernel D: n = LN(hg @ Wn + bn); cls = softmax(n).  1 wave / node.
// ---------------------------------------------------------------------------
__global__ __launch_bounds__(256) void k_node_head(
    const float* __restrict__ hg,
    const float* __restrict__ Wn, const float* __restrict__ bn,
    const float* __restrict__ gn, const float* __restrict__ ben,
    float* __restrict__ nout, float* __restrict__ cls)
{
    __shared__ float wns[384 * 5];
    const int tid = threadIdx.x;
    for (int i = tid; i < 1920; i += 256) wns[i] = Wn[i];
    __syncthreads();
    const int wid = tid >> 6, lane = tid & 63;
    const int node = blockIdx.x * 4 + wid;
    float a0 = 0, a1 = 0, a2 = 0, a3 = 0, a4 = 0;
    const float* row = hg + (size_t)node * 384;
    for (int k = lane; k < 384; k += 64) {
        float v = row[k];
        const float* wp = &wns[k * 5];
        a0 += v * wp[0]; a1 += v * wp[1]; a2 += v * wp[2];
        a3 += v * wp[3]; a4 += v * wp[4];
    }
    for (int o = 32; o > 0; o >>= 1) {
        a0 += __shfl_down(a0, o); a1 += __shfl_down(a1, o);
        a2 += __shfl_down(a2, o); a3 += __shfl_down(a3, o);
        a4 += __shfl_down(a4, o);
    }
    if (lane == 0) {
        float v[5] = { a0 + bn[0], a1 + bn[1], a2 + bn[2], a3 + bn[3], a4 + bn[4] };
        float mu = (v[0] + v[1] + v[2] + v[3] + v[4]) * 0.2f;
        float var = 0.0f;
        #pragma unroll
        for (int c = 0; c < 5; ++c) { float d = v[c] - mu; var += d * d; }
        var *= 0.2f;
        float rs = rsqrtf(var + 1e-5f);
        float nv[5]; float m = -1e30f;
        #pragma unroll
        for (int c = 0; c < 5; ++c) {
            nv[c] = (v[c] - mu) * rs * gn[c] + ben[c];
            m = fmaxf(m, nv[c]);
        }
        #pragma unroll
        for (int c = 0; c < 5; ++c) nout[(size_t)node * 5 + c] = nv[c];
        float ex[5]; float s = 0.0f;
        #pragma unroll
        for (int c = 0; c < 5; ++c) { ex[c] = expf(nv[c] - m); s += ex[c]; }
        float inv = 1.0f / s;
        #pragma unroll
        for (int c = 0; c < 5; ++c) cls[(size_t)node * 5 + c] = ex[c] * inv;
    }
}

// ---------------------------------------------------------------------------
// Kernel E: edge MLP.  R7 structure (Er=8, [e][c] layout, conflict-free)
// with __launch_bounds__(256,3): VGPR cap 168 so the ~115-live-reg set
// allocates WITHOUT spill (R7's (256,4) forced 64 VGPR -> 372 MB scratch
// traffic).  At <=128 VGPR the HW still gives 4 waves/SIMD; LDS 29.7 KB
// allows 4 blocks/CU.
// 64 edges/block (4000 blocks), 256 threads = 8 half-waves.
// hw = tid>>5 owns 8 edges; jg = tid&31 owns j = jg*10..+9 (jg<30 active).
// Per 2-kl per thread: 8 broadcast ds_read_b64 + 10 W float2 + 160 FMA.
// LN + W2 epilogue in-register via __shfl_xor width-32.
// ---------------------------------------------------------------------------
#define EM_KC 112
#define EM_ST 116

__global__ __launch_bounds__(256, 3) void k_edge_mlp(
    const float* __restrict__ hg, const float* __restrict__ cls,
    const int* __restrict__ srcI, const int* __restrict__ dstI,
    const float* __restrict__ polar,
    const float* __restrict__ W1, const float* __restrict__ b1,
    const float* __restrict__ g1, const float* __restrict__ be1,
    const float* __restrict__ W2, const float* __restrict__ b2,
    float* __restrict__ eout)
{
    __shared__ __align__(16) float xs[64 * EM_ST];   // [e][cl], 29.7 KB
    const int tid = threadIdx.x;
    const int e0  = blockIdx.x * 64;
    const int hw  = tid >> 5;            // half-wave id, 0..7
    const int jg  = tid & 31;            // 0..31, active jg<30
    const bool act = (jg < 30);
    const float actf = act ? 1.f : 0.f;
    const int j0  = (act ? jg : 29) * 10;
    const int eb  = hw * 8;

    // staging identity: 4 e-groups x 64 c-lanes
    const int c_sel = tid & 63;
    const int e_grp = tid >> 6;          // 0..3, 16 edges each

    float a[10][8];                      // [j][e]
    #pragma unroll
    for (int r = 0; r < 10; ++r)
        #pragma unroll
        for (int e = 0; e < 8; ++e) a[r][e] = 0.f;

    for (int t = 0; t < 7; ++t) {
        // ---- stage x[e][cl]: lanes = consecutive c -> coalesced global,
        //      conflict-free LDS writes ----
        for (int eo = 0; eo < 16; ++eo) {
            const int e  = e_grp * 16 + eo;
            const int eg = e0 + e;
            const int se = srcI[eg], de = dstI[eg];
            for (int c = c_sel; c < EM_KC; c += 64) {
                const int cg = t * EM_KC + c;
                float v;
                if (cg < 384)      v = hg[(size_t)se * 384 + cg];
                else if (cg < 389) v = cls[(size_t)se * 5 + (cg - 384)];
                else if (cg < 395) v = polar[(size_t)eg * 6 + (cg - 389)];
                else if (cg < 779) v = hg[(size_t)de * 384 + (cg - 395)];
                else               v = cls[(size_t)de * 5 + (cg - 779)];
                xs[e * EM_ST + c] = v;
            }
        }
        __syncthreads();

        const float* wbase = W1 + (size_t)(t * EM_KC) * 300 + j0;
        for (int kq = 0; kq < EM_KC / 2; ++kq) {
            float2 xv[8];
            #pragma unroll
            for (int i = 0; i < 8; ++i)
                xv[i] = *reinterpret_cast<const float2*>(&xs[(eb + i) * EM_ST + kq * 2]);
            const float* wp = wbase + (size_t)(kq * 2) * 300;
            #pragma unroll
            for (int kk = 0; kk < 2; ++kk) {
                const float2 wA = *reinterpret_cast<const float2*>(wp + kk * 300 + 0);
                const float2 wB = *reinterpret_cast<const float2*>(wp + kk * 300 + 2);
                const float2 wC = *reinterpret_cast<const float2*>(wp + kk * 300 + 4);
                const float2 wD = *reinterpret_cast<const float2*>(wp + kk * 300 + 6);
                const float2 wE = *reinterpret_cast<const float2*>(wp + kk * 300 + 8);
                const float wr[10] = { wA.x, wA.y, wB.x, wB.y, wC.x, wC.y,
                                       wD.x, wD.y, wE.x, wE.y };
                const float xk[8] = {
                    kk ? xv[0].y : xv[0].x, kk ? xv[1].y : xv[1].x,
                    kk ? xv[2].y : xv[2].x, kk ? xv[3].y : xv[3].x,
                    kk ? xv[4].y : xv[4].x, kk ? xv[5].y : xv[5].x,
                    kk ? xv[6].y : xv[6].x, kk ? xv[7].y : xv[7].x };
                #pragma unroll
                for (int r = 0; r < 10; ++r)
                    #pragma unroll
                    for (int e = 0; e < 8; ++e) a[r][e] += wr[r] * xk[e];
            }
        }
        __syncthreads();
    }

    // ---- bias ----
    {
        const float2 bA = *reinterpret_cast<const float2*>(&b1[j0 + 0]);
        const float2 bB = *reinterpret_cast<const float2*>(&b1[j0 + 2]);
        const float2 bC = *reinterpret_cast<const float2*>(&b1[j0 + 4]);
        const float2 bD = *reinterpret_cast<const float2*>(&b1[j0 + 6]);
        const float2 bE = *reinterpret_cast<const float2*>(&b1[j0 + 8]);
        const float br[10] = { bA.x, bA.y, bB.x, bB.y, bC.x, bC.y,
                               bD.x, bD.y, bE.x, bE.y };
        #pragma unroll
        for (int r = 0; r < 10; ++r)
            #pragma unroll
            for (int e = 0; e < 8; ++e) a[r][e] += br[r];
    }

    // ---- LN stats: butterfly over the 32-lane jg dimension ----
    float mu[8], rs[8];
    #pragma unroll
    for (int e = 0; e < 8; ++e) {
        float s = 0.f, q = 0.f;
        #pragma unroll
        for (int r = 0; r < 10; ++r) { s += a[r][e]; q += a[r][e] * a[r][e]; }
        s *= actf; q *= actf;
        #pragma unroll
        for (int o = 16; o > 0; o >>= 1) {
            s += __shfl_xor(s, o, 32);
            q += __shfl_xor(q, o, 32);
        }
        mu[e] = s * (1.f / 300.f);
        float var = q * (1.f / 300.f) - mu[e] * mu[e];
        rs[e] = rsqrtf(var + 1e-5f);
    }

    // ---- LN + relu + layer-2 partials + butterfly reduce ----
    const float2 gA = *reinterpret_cast<const float2*>(&g1[j0 + 0]);
    const float2 gB = *reinterpret_cast<const float2*>(&g1[j0 + 2]);
    const float2 gC = *reinterpret_cast<const float2*>(&g1[j0 + 4]);
    const float2 gD = *reinterpret_cast<const float2*>(&g1[j0 + 6]);
    const float2 gE = *reinterpret_cast<const float2*>(&g1[j0 + 8]);
    const float2 eA = *reinterpret_cast<const float2*>(&be1[j0 + 0]);
    const float2 eB = *reinterpret_cast<const float2*>(&be1[j0 + 2]);
    const float2 eC = *reinterpret_cast<const float2*>(&be1[j0 + 4]);
    const float2 eD = *reinterpret_cast<const float2*>(&be1[j0 + 6]);
    const float2 eE = *reinterpret_cast<const float2*>(&be1[j0 + 8]);
    const float gr[10] = { gA.x, gA.y, gB.x, gB.y, gC.x, gC.y, gD.x, gD.y, gE.x, gE.y };
    const float er[10] = { eA.x, eA.y, eB.x, eB.y, eC.x, eC.y, eD.x, eD.y, eE.x, eE.y };
    float w20[10], w21[10];
    #pragma unroll
    for (int r = 0; r < 10; ++r) {
        const float2 w2 = *reinterpret_cast<const float2*>(&W2[(j0 + r) * 2]);
        w20[r] = w2.x; w21[r] = w2.y;
    }
    float o0[8], o1[8];
    #pragma unroll
    for (int e = 0; e < 8; ++e) {
        float s0 = 0.f, s1 = 0.f;
        #pragma unroll
        for (int r = 0; r < 10; ++r) {
            float y = fmaxf((a[r][e] - mu[e]) * rs[e] * gr[r] + er[r], 0.f);
            s0 += y * w20[r];
            s1 += y * w21[r];
        }
        s0 *= actf; s1 *= actf;
        #pragma unroll
        for (int o = 16; o > 0; o >>= 1) {
            s0 += __shfl_xor(s0, o, 32);
            s1 += __shfl_xor(s1, o, 32);
        }
        o0[e] = s0; o1[e] = s1;
    }
    if (jg == 0) {
        const float b20 = b2[0], b21 = b2[1];
        #pragma unroll
        for (int e = 0; e < 8; ++e)
            *reinterpret_cast<float2*>(&eout[(size_t)(e0 + eb + e) * 2]) =
                make_float2(o0[e] + b20, o1[e] + b21);
    }
}

// ---------------------------------------------------------------------------
extern "C" void kernel_launch(void* const* d_in, const int* in_sizes, int n_in,
                              void* d_out, int out_size, void* d_ws, size_t ws_size,
                              hipStream_t stream)
{
    const float* h     = (const float*)d_in[0];
    const int*   src   = (const int*)d_in[1];
    const int*   dst   = (const int*)d_in[2];
    const int*   pos   = (const int*)d_in[3];
    const float* dist  = (const float*)d_in[4];
    const float* polar = (const float*)d_in[5];
    const float* Wp0   = (const float*)d_in[6];
    const float* bp0   = (const float*)d_in[7];
    const float* gp0   = (const float*)d_in[8];
    const float* bep0  = (const float*)d_in[9];
    const float* Wp1   = (const float*)d_in[10];
    const float* bp1   = (const float*)d_in[11];
    const float* gp1   = (const float*)d_in[12];
    const float* bep1  = (const float*)d_in[13];
    const float* Wg    = (const float*)d_in[14];
    const float* bg    = (const float*)d_in[15];
    const float* gg    = (const float*)d_in[16];
    const float* beg   = (const float*)d_in[17];
    const float* Wn    = (const float*)d_in[18];
    const float* bn    = (const float*)d_in[19];
    const float* gn    = (const float*)d_in[20];
    const float* ben   = (const float*)d_in[21];
    const float* W1    = (const float*)d_in[22];
    const float* b1    = (const float*)d_in[23];
    const float* g1    = (const float*)d_in[24];
    const float* be1   = (const float*)d_in[25];
    const float* W2    = (const float*)d_in[26];
    const float* b2    = (const float*)d_in[27];

    float* ws  = (float*)d_ws;
    float* acc = ws + ACC_OFF;
    float* hp  = ws + HP_OFF;
    float* hg  = hp;                        // aliased (see k_gemm_hg comment)
    float* cls = ws + CLS_OFF;
    float* nout = (float*)d_out;            // 40000*5
    float* eout = (float*)d_out + 200000;   // 256000*2

    k_zero<<<2048, 256, 0, stream>>>((float4*)acc, ACC_FLOATS / 4);

    k_proj<<<2500, 192, 0, stream>>>(h, Wp0, bp0, gp0, bep0,
                                     Wp1, bp1, gp1, bep1, hp);
    k_scatter<<<96000, 256, 0, stream>>>(hp, src, dst, pos, dist, acc);
    k_gemm_hg<<<1250, 256, 0, stream>>>(hp, acc, Wg, bg, gg, beg, hg);
    k_node_head<<<10000, 256, 0, stream>>>(hg, Wn, bn, gn, ben, nout, cls);
    k_edge_mlp<<<4000, 256, 0, stream>>>(hg, cls, src, dst, polar,
                                         W1, b1, g1, be1, W2, b2, eout);
}

// Round 10
// 3007.999 us; speedup vs baseline: 2.0302x; 1.5398x over previous
//
#include <hip/hip_runtime.h>
#include <math.h>

// Problem constants
#define NN 40000
#define NE 256000

// Workspace layout (floats), total 61,640,000 floats = 246.6 MB
//  acc : 40000*1152 = 46,080,000   [r|b|l] scatter accumulators.
//        After k_gemm_hg consumes acc, the region is REUSED for
//        u (40000*300 @ +0) and v (40000*300 @ +12,000,000).
//  hp  : 40000*384  = 15,360,000   projected node features; REUSED as hg
//  cls : 40000*5    =    200,000   softmax probs
static const size_t ACC_OFF = 0;
static const size_t HP_OFF  = 46080000;
static const size_t CLS_OFF = 61440000;
static const size_t V_OFF   = 12000000;   // v inside acc region
#define ACC_FLOATS 46080000

// ---------------------------------------------------------------------------
__global__ __launch_bounds__(256) void k_zero(float4* __restrict__ p, int n4)
{
    int stride = gridDim.x * 256;
    for (int i = blockIdx.x * 256 + threadIdx.x; i < n4; i += stride)
        p[i] = make_float4(0.f, 0.f, 0.f, 0.f);
}

// ---------------------------------------------------------------------------
// Kernel A: fused projections, register-blocked (unchanged).
// ---------------------------------------------------------------------------
__global__ __launch_bounds__(192) void k_proj(
    const float* __restrict__ h,
    const float* __restrict__ Wp0, const float* __restrict__ bp0,
    const float* __restrict__ gp0, const float* __restrict__ bep0,
    const float* __restrict__ Wp1, const float* __restrict__ bp1,
    const float* __restrict__ gp1, const float* __restrict__ bep1,
    float* __restrict__ hp)
{
    __shared__ __align__(16) float xs[384 * 16];   // [c][n], 24.6 KB
    __shared__ float2 stats0[16], stats1[16];
    const int tid = threadIdx.x;
    const int n0  = blockIdx.x * 16;
    const int jg  = tid % 48;
    const int nt  = tid / 48;
    const int j0  = jg * 4;

    for (int idx = tid; idx < 384 * 16; idx += 192) {
        int n = idx & 15, c = idx >> 4;
        xs[c * 16 + n] = h[(size_t)(n0 + n) * 384 + c];
    }
    __syncthreads();

    float a0[4][4], a1[4][4];
    #pragma unroll
    for (int r = 0; r < 4; ++r)
        #pragma unroll
        for (int n = 0; n < 4; ++n) { a0[r][n] = 0.f; a1[r][n] = 0.f; }

    #pragma unroll 2
    for (int k = 0; k < 300; ++k) {
        const float4 x = *reinterpret_cast<const float4*>(&xs[k * 16 + nt * 4]);
        const float4 w = *reinterpret_cast<const float4*>(&Wp0[k * 192 + j0]);
        const float wr[4] = { w.x, w.y, w.z, w.w };
        const float xr[4] = { x.x, x.y, x.z, x.w };
        #pragma unroll
        for (int r = 0; r < 4; ++r)
            #pragma unroll
            for (int n = 0; n < 4; ++n) a0[r][n] += wr[r] * xr[n];
    }
    #pragma unroll 2
    for (int k = 0; k < 84; ++k) {
        const float4 x = *reinterpret_cast<const float4*>(&xs[(300 + k) * 16 + nt * 4]);
        const float4 w = *reinterpret_cast<const float4*>(&Wp1[k * 192 + j0]);
        const float wr[4] = { w.x, w.y, w.z, w.w };
        const float xr[4] = { x.x, x.y, x.z, x.w };
        #pragma unroll
        for (int r = 0; r < 4; ++r)
            #pragma unroll
            for (int n = 0; n < 4; ++n) a1[r][n] += wr[r] * xr[n];
    }
    {
        const float4 b0 = *reinterpret_cast<const float4*>(&bp0[j0]);
        const float4 b1 = *reinterpret_cast<const float4*>(&bp1[j0]);
        const float b0r[4] = { b0.x, b0.y, b0.z, b0.w };
        const float b1r[4] = { b1.x, b1.y, b1.z, b1.w };
        #pragma unroll
        for (int r = 0; r < 4; ++r)
            #pragma unroll
            for (int n = 0; n < 4; ++n) { a0[r][n] += b0r[r]; a1[r][n] += b1r[r]; }
    }
    __syncthreads();
    float2* red = (float2*)xs;

    #pragma unroll
    for (int n = 0; n < 4; ++n) {
        float s = 0.f, q = 0.f;
        #pragma unroll
        for (int r = 0; r < 4; ++r) { s += a0[r][n]; q += a0[r][n] * a0[r][n]; }
        red[jg * 16 + nt * 4 + n] = make_float2(s, q);
    }
    __syncthreads();
    if (tid < 16) {
        float s = 0.f, q = 0.f;
        for (int g = 0; g < 48; ++g) { float2 v = red[g * 16 + tid]; s += v.x; q += v.y; }
        float mu = s * (1.f / 192.f);
        float var = q * (1.f / 192.f) - mu * mu;
        stats0[tid] = make_float2(mu, rsqrtf(var + 1e-5f));
    }
    __syncthreads();
    #pragma unroll
    for (int n = 0; n < 4; ++n) {
        float s = 0.f, q = 0.f;
        #pragma unroll
        for (int r = 0; r < 4; ++r) { s += a1[r][n]; q += a1[r][n] * a1[r][n]; }
        red[jg * 16 + nt * 4 + n] = make_float2(s, q);
    }
    {
        const float4 g = *reinterpret_cast<const float4*>(&gp0[j0]);
        const float4 be = *reinterpret_cast<const float4*>(&bep0[j0]);
        const float gr[4] = { g.x, g.y, g.z, g.w };
        const float br[4] = { be.x, be.y, be.z, be.w };
        #pragma unroll
        for (int n = 0; n < 4; ++n) {
            float2 st = stats0[nt * 4 + n];
            float4 o;
            o.x = fmaxf((a0[0][n] - st.x) * st.y * gr[0] + br[0], 0.f);
            o.y = fmaxf((a0[1][n] - st.x) * st.y * gr[1] + br[1], 0.f);
            o.z = fmaxf((a0[2][n] - st.x) * st.y * gr[2] + br[2], 0.f);
            o.w = fmaxf((a0[3][n] - st.x) * st.y * gr[3] + br[3], 0.f);
            *reinterpret_cast<float4*>(&hp[(size_t)(n0 + nt * 4 + n) * 384 + j0]) = o;
        }
    }
    __syncthreads();
    if (tid < 16) {
        float s = 0.f, q = 0.f;
        for (int g = 0; g < 48; ++g) { float2 v = red[g * 16 + tid]; s += v.x; q += v.y; }
        float mu = s * (1.f / 192.f);
        float var = q * (1.f / 192.f) - mu * mu;
        stats1[tid] = make_float2(mu, rsqrtf(var + 1e-5f));
    }
    __syncthreads();
    {
        const float4 g = *reinterpret_cast<const float4*>(&gp1[j0]);
        const float4 be = *reinterpret_cast<const float4*>(&bep1[j0]);
        const float gr[4] = { g.x, g.y, g.z, g.w };
        const float br[4] = { be.x, be.y, be.z, be.w };
        #pragma unroll
        for (int n = 0; n < 4; ++n) {
            float2 st = stats1[nt * 4 + n];
            float4 o;
            o.x = fmaxf((a1[0][n] - st.x) * st.y * gr[0] + br[0], 0.f);
            o.y = fmaxf((a1[1][n] - st.x) * st.y * gr[1] + br[1], 0.f);
            o.z = fmaxf((a1[2][n] - st.x) * st.y * gr[2] + br[2], 0.f);
            o.w = fmaxf((a1[3][n] - st.x) * st.y * gr[3] + br[3], 0.f);
            *reinterpret_cast<float4*>(&hp[(size_t)(n0 + nt * 4 + n) * 384 + 192 + j0]) = o;
        }
    }
}

// ---------------------------------------------------------------------------
// Kernel B: edge scatter (unchanged).
// ---------------------------------------------------------------------------
__global__ __launch_bounds__(256) void k_scatter(
    const float* __restrict__ hp,
    const int* __restrict__ src, const int* __restrict__ dst,
    const int* __restrict__ pos, const float* __restrict__ dist,
    float* __restrict__ acc)
{
    int gid = blockIdx.x * 256 + threadIdx.x;   // NE*96 total
    int e  = gid / 96;
    int f4 = (gid - e * 96) * 4;
    int p = pos[e];
    if (p >= 3) return;
    float w = dist[e];
    int s = src[e], d = dst[e];
    const float4 v = *reinterpret_cast<const float4*>(&hp[(size_t)s * 384 + f4]);
    float* o = &acc[(size_t)d * 1152 + (size_t)p * 384 + f4];
    atomicAdd(o + 0, v.x * w);
    atomicAdd(o + 1, v.y * w);
    atomicAdd(o + 2, v.z * w);
    atomicAdd(o + 3, v.w * w);
}

// ---------------------------------------------------------------------------
// Kernel C: hg = relu(LN(hc @ Wg + bg)) (unchanged from R6).
// ---------------------------------------------------------------------------
__global__ __launch_bounds__(256) void k_gemm_hg(
    const float* __restrict__ hp, const float* __restrict__ acc,
    const float* __restrict__ Wg, const float* __restrict__ bg,
    const float* __restrict__ gg, const float* __restrict__ beg,
    float* __restrict__ hg)
{
    __shared__ __align__(16) float xs[384 * 32];    // [c][n], 48 KB
    const int tid = threadIdx.x;
    const int n0  = blockIdx.x * 32;
    const int jg  = tid & 31;           // 32 groups * 12 j = 384
    const int nt  = tid >> 5;           // 8 groups * 4 nodes = 32
    const int j0  = jg * 12;
    const int nb  = nt * 4;
    const int ns  = tid & 31;           // staging: fixed node per thread

    float a[12][4];
    #pragma unroll
    for (int r = 0; r < 12; ++r)
        #pragma unroll
        for (int n = 0; n < 4; ++n) a[r][n] = 0.f;

    for (int t = 0; t < 5; ++t) {
        const float* srow;
        if (t == 0)      srow = hp  + (size_t)(n0 + ns) * 384;
        else if (t < 4)  srow = acc + (size_t)(n0 + ns) * 1152 + (size_t)(t - 1) * 384;
        else             srow = acc + (size_t)(n0 + ns) * 1152;           // t = r
        for (int c = tid >> 5; c < 384; c += 8)
            xs[c * 32 + ns] = srow[c];
        __syncthreads();

        const float* wp = Wg + (size_t)t * 384 * 384 + j0;
        for (int kl = 0; kl < 384; ++kl) {
            const float4 w0 = *reinterpret_cast<const float4*>(wp + 0);
            const float4 w1 = *reinterpret_cast<const float4*>(wp + 4);
            const float4 w2 = *reinterpret_cast<const float4*>(wp + 8);
            wp += 384;
            const float4 x = *reinterpret_cast<const float4*>(&xs[kl * 32 + nb]);
            const float wr[12] = { w0.x, w0.y, w0.z, w0.w, w1.x, w1.y, w1.z, w1.w,
                                   w2.x, w2.y, w2.z, w2.w };
            const float xr[4]  = { x.x, x.y, x.z, x.w };
            #pragma unroll
            for (int r = 0; r < 12; ++r)
                #pragma unroll
                for (int n = 0; n < 4; ++n) a[r][n] += wr[r] * xr[n];
        }
        __syncthreads();
    }
    {
        const float4 b0 = *reinterpret_cast<const float4*>(&bg[j0 + 0]);
        const float4 b1 = *reinterpret_cast<const float4*>(&bg[j0 + 4]);
        const float4 b2 = *reinterpret_cast<const float4*>(&bg[j0 + 8]);
        const float br[12] = { b0.x, b0.y, b0.z, b0.w, b1.x, b1.y, b1.z, b1.w,
                               b2.x, b2.y, b2.z, b2.w };
        #pragma unroll
        for (int r = 0; r < 12; ++r)
            #pragma unroll
            for (int n = 0; n < 4; ++n) a[r][n] += br[r];
    }
    const float4 gA = *reinterpret_cast<const float4*>(&gg[j0 + 0]);
    const float4 gB = *reinterpret_cast<const float4*>(&gg[j0 + 4]);
    const float4 gC = *reinterpret_cast<const float4*>(&gg[j0 + 8]);
    const float4 eA = *reinterpret_cast<const float4*>(&beg[j0 + 0]);
    const float4 eB = *reinterpret_cast<const float4*>(&beg[j0 + 4]);
    const float4 eC = *reinterpret_cast<const float4*>(&beg[j0 + 8]);
    const float gr[12] = { gA.x, gA.y, gA.z, gA.w, gB.x, gB.y, gB.z, gB.w,
                           gC.x, gC.y, gC.z, gC.w };
    const float er[12] = { eA.x, eA.y, eA.z, eA.w, eB.x, eB.y, eB.z, eB.w,
                           eC.x, eC.y, eC.z, eC.w };
    #pragma unroll
    for (int n = 0; n < 4; ++n) {
        float s = 0.f, q = 0.f;
        #pragma unroll
        for (int r = 0; r < 12; ++r) { s += a[r][n]; q += a[r][n] * a[r][n]; }
        #pragma unroll
        for (int o = 16; o > 0; o >>= 1) {
            s += __shfl_xor(s, o, 32);
            q += __shfl_xor(q, o, 32);
        }
        float mu = s * (1.f / 384.f);
        float var = q * (1.f / 384.f) - mu * mu;
        float rs = rsqrtf(var + 1e-5f);
        float out[12];
        #pragma unroll
        for (int r = 0; r < 12; ++r)
            out[r] = fmaxf((a[r][n] - mu) * rs * gr[r] + er[r], 0.f);
        float* orow = &hg[(size_t)(n0 + nb + n) * 384 + j0];
        *reinterpret_cast<float4*>(orow + 0) = make_float4(out[0], out[1], out[2], out[3]);
        *reinterpret_cast<float4*>(orow + 4) = make_float4(out[4], out[5], out[6], out[7]);
        *reinterpret_cast<float4*>(orow + 8) = make_float4(out[8], out[9], out[10], out[11]);
    }
}

// ---------------------------------------------------------------------------
// Kernel D: n = LN(hg @ Wn + bn); cls = softmax(n).  1 wave / node.
// ---------------------------------------------------------------------------
__global__ __launch_bounds__(256) void k_node_head(
    const float* __restrict__ hg,
    const float* __restrict__ Wn, const float* __restrict__ bn,
    const float* __restrict__ gn, const float* __restrict__ ben,
    float* __restrict__ nout, float* __restrict__ cls)
{
    __shared__ float wns[384 * 5];
    const int tid = threadIdx.x;
    for (int i = tid; i < 1920; i += 256) wns[i] = Wn[i];
    __syncthreads();
    const int wid = tid >> 6, lane = tid & 63;
    const int node = blockIdx.x * 4 + wid;
    float a0 = 0, a1 = 0, a2 = 0, a3 = 0, a4 = 0;
    const float* row = hg + (size_t)node * 384;
    for (int k = lane; k < 384; k += 64) {
        float v = row[k];
        const float* wp = &wns[k * 5];
        a0 += v * wp[0]; a1 += v * wp[1]; a2 += v * wp[2];
        a3 += v * wp[3]; a4 += v * wp[4];
    }
    for (int o = 32; o > 0; o >>= 1) {
        a0 += __shfl_down(a0, o); a1 += __shfl_down(a1, o);
        a2 += __shfl_down(a2, o); a3 += __shfl_down(a3, o);
        a4 += __shfl_down(a4, o);
    }
    if (lane == 0) {
        float v[5] = { a0 + bn[0], a1 + bn[1], a2 + bn[2], a3 + bn[3], a4 + bn[4] };
        float mu = (v[0] + v[1] + v[2] + v[3] + v[4]) * 0.2f;
        float var = 0.0f;
        #pragma unroll
        for (int c = 0; c < 5; ++c) { float d = v[c] - mu; var += d * d; }
        var *= 0.2f;
        float rs = rsqrtf(var + 1e-5f);
        float nv[5]; float m = -1e30f;
        #pragma unroll
        for (int c = 0; c < 5; ++c) {
            nv[c] = (v[c] - mu) * rs * gn[c] + ben[c];
            m = fmaxf(m, nv[c]);
        }
        #pragma unroll
        for (int c = 0; c < 5; ++c) nout[(size_t)node * 5 + c] = nv[c];
        float ex[5]; float s = 0.0f;
        #pragma unroll
        for (int c = 0; c < 5; ++c) { ex[c] = expf(nv[c] - m); s += ex[c]; }
        float inv = 1.0f / s;
        #pragma unroll
        for (int c = 0; c < 5; ++c) cls[(size_t)node * 5 + c] = ex[c] * inv;
    }
}

// ---------------------------------------------------------------------------
// Kernel E1: per-node edge-MLP projections.
//   u[n][j] = sum_c hg[n][c]*W1[c][j]       + sum_cc cls[n][cc]*W1[384+cc][j]
//   v[n][j] = sum_c hg[n][c]*W1[395+c][j]   + sum_cc cls[n][cc]*W1[779+cc][j]
// The edge MLP's x@W1 then equals u[src] + v[dst] + C*polar + b1 exactly
// (summation reorder only).  18.7 GF replaces the old 118 GF of per-edge
// node-feature GEMM (each node was re-GEMMed ~6.4x).
// 32 nodes/block (1250 blocks), 256 threads; jg = tid&31 owns j = jg*10..+9
// (jg<30 active), nt = tid>>5 owns 4 nodes.  Two passes (u, v) over ONE
// staged hg tile; acc = 40 VGPR -> no spill.
// ---------------------------------------------------------------------------
__global__ __launch_bounds__(256) void k_node_uv(
    const float* __restrict__ hg, const float* __restrict__ cls,
    const float* __restrict__ W1,
    float* __restrict__ u, float* __restrict__ v)
{
    __shared__ __align__(16) float xs[384 * 32];   // [c][n], 48 KB
    __shared__ __align__(16) float cs[5 * 32];     // [cc][n]
    const int tid = threadIdx.x;
    const int n0  = blockIdx.x * 32;
    const int jg  = tid & 31;
    const int nt  = tid >> 5;
    const bool act = (jg < 30);
    const int j0  = (act ? jg : 29) * 10;
    const int nb  = nt * 4;
    const int ns  = tid & 31;

    const float* srow = hg + (size_t)(n0 + ns) * 384;
    for (int c = tid >> 5; c < 384; c += 8)
        xs[c * 32 + ns] = srow[c];
    if (tid < 160) {
        int n = tid & 31, cc = tid >> 5;
        cs[cc * 32 + n] = cls[(size_t)(n0 + n) * 5 + cc];
    }
    __syncthreads();

    for (int pass = 0; pass < 2; ++pass) {
        const float* wb  = W1 + (size_t)(pass ? 395 : 0) * 300 + j0;
        const float* wcb = W1 + (size_t)(pass ? 779 : 384) * 300 + j0;
        float a[10][4];
        #pragma unroll
        for (int r = 0; r < 10; ++r)
            #pragma unroll
            for (int n = 0; n < 4; ++n) a[r][n] = 0.f;

        const float* wp = wb;
        for (int kl = 0; kl < 384; ++kl) {
            const float2 wA = *reinterpret_cast<const float2*>(wp + 0);
            const float2 wB = *reinterpret_cast<const float2*>(wp + 2);
            const float2 wC = *reinterpret_cast<const float2*>(wp + 4);
            const float2 wD = *reinterpret_cast<const float2*>(wp + 6);
            const float2 wE = *reinterpret_cast<const float2*>(wp + 8);
            wp += 300;
            const float4 x = *reinterpret_cast<const float4*>(&xs[kl * 32 + nb]);
            const float wr[10] = { wA.x, wA.y, wB.x, wB.y, wC.x, wC.y,
                                   wD.x, wD.y, wE.x, wE.y };
            const float xr[4]  = { x.x, x.y, x.z, x.w };
            #pragma unroll
            for (int r = 0; r < 10; ++r)
                #pragma unroll
                for (int n = 0; n < 4; ++n) a[r][n] += wr[r] * xr[n];
        }
        for (int cc = 0; cc < 5; ++cc) {
            const float* wq = wcb + (size_t)cc * 300;
            const float2 wA = *reinterpret_cast<const float2*>(wq + 0);
            const float2 wB = *reinterpret_cast<const float2*>(wq + 2);
            const float2 wC = *reinterpret_cast<const float2*>(wq + 4);
            const float2 wD = *reinterpret_cast<const float2*>(wq + 6);
            const float2 wE = *reinterpret_cast<const float2*>(wq + 8);
            const float4 x = *reinterpret_cast<const float4*>(&cs[cc * 32 + nb]);
            const float wr[10] = { wA.x, wA.y, wB.x, wB.y, wC.x, wC.y,
                                   wD.x, wD.y, wE.x, wE.y };
            const float xr[4]  = { x.x, x.y, x.z, x.w };
            #pragma unroll
            for (int r = 0; r < 10; ++r)
                #pragma unroll
                for (int n = 0; n < 4; ++n) a[r][n] += wr[r] * xr[n];
        }
        if (act) {
            float* dstp = (pass ? v : u);
            #pragma unroll
            for (int n = 0; n < 4; ++n) {
                float* orow = dstp + (size_t)(n0 + nb + n) * 300 + j0;
                #pragma unroll
                for (int rr = 0; rr < 5; ++rr)
                    *reinterpret_cast<float2*>(orow + 2 * rr) =
                        make_float2(a[2 * rr][n], a[2 * rr + 1][n]);
            }
        }
    }
}

// ---------------------------------------------------------------------------
// Kernel E2: per-edge finish.  y = u[src] + v[dst] + C*polar + b1;
// e = relu(LN(y)) @ W2 + b2.  Gather-bound (614 MB of u/v rows from L3).
// 32 edges/block (8000 blocks), 256 threads = 8 half-waves; hw owns 4 edges,
// jg = tid&31 owns j = jg*10..+9 (jg<30 active).  LN/W2 in-register via
// __shfl_xor width-32 (R9 epilogue).  acc y = 40 VGPR -> no spill.
// ---------------------------------------------------------------------------
__global__ __launch_bounds__(256) void k_edge_small(
    const float* __restrict__ u, const float* __restrict__ v,
    const int* __restrict__ srcI, const int* __restrict__ dstI,
    const float* __restrict__ polar,
    const float* __restrict__ W1, const float* __restrict__ b1,
    const float* __restrict__ g1, const float* __restrict__ be1,
    const float* __restrict__ W2, const float* __restrict__ b2,
    float* __restrict__ eout)
{
    const int tid = threadIdx.x;
    const int e0  = blockIdx.x * 32;
    const int hw  = tid >> 5;
    const int jg  = tid & 31;
    const bool act = (jg < 30);
    const float actf = act ? 1.f : 0.f;
    const int j0  = (act ? jg : 29) * 10;
    const int eb  = hw * 4;

    // y init with b1
    float y[10][4];
    {
        const float2 bA = *reinterpret_cast<const float2*>(&b1[j0 + 0]);
        const float2 bB = *reinterpret_cast<const float2*>(&b1[j0 + 2]);
        const float2 bC = *reinterpret_cast<const float2*>(&b1[j0 + 4]);
        const float2 bD = *reinterpret_cast<const float2*>(&b1[j0 + 6]);
        const float2 bE = *reinterpret_cast<const float2*>(&b1[j0 + 8]);
        const float br[10] = { bA.x, bA.y, bB.x, bB.y, bC.x, bC.y,
                               bD.x, bD.y, bE.x, bE.y };
        #pragma unroll
        for (int r = 0; r < 10; ++r)
            #pragma unroll
            for (int e = 0; e < 4; ++e) y[r][e] = br[r];
    }

    // u[src] + v[dst] gathers
    #pragma unroll
    for (int e = 0; e < 4; ++e) {
        const int eg = e0 + eb + e;
        const int se = srcI[eg], de = dstI[eg];
        const float* ur = u + (size_t)se * 300 + j0;
        const float* vr = v + (size_t)de * 300 + j0;
        #pragma unroll
        for (int rr = 0; rr < 5; ++rr) {
            const float2 uu = *reinterpret_cast<const float2*>(ur + 2 * rr);
            const float2 vv = *reinterpret_cast<const float2*>(vr + 2 * rr);
            y[2 * rr][e]     += uu.x + vv.x;
            y[2 * rr + 1][e] += uu.y + vv.y;
        }
    }

    // polar term: 6 k, weights W1 rows 389..394 (L1-hot)
    float pol[4][6];
    #pragma unroll
    for (int e = 0; e < 4; ++e) {
        const float* pr = polar + (size_t)(e0 + eb + e) * 6;
        const float2 p0 = *reinterpret_cast<const float2*>(pr + 0);
        const float2 p1 = *reinterpret_cast<const float2*>(pr + 2);
        const float2 p2 = *reinterpret_cast<const float2*>(pr + 4);
        pol[e][0] = p0.x; pol[e][1] = p0.y; pol[e][2] = p1.x;
        pol[e][3] = p1.y; pol[e][4] = p2.x; pol[e][5] = p2.y;
    }
    for (int kk = 0; kk < 6; ++kk) {
        const float* wq = W1 + (size_t)(389 + kk) * 300 + j0;
        const float2 wA = *reinterpret_cast<const float2*>(wq + 0);
        const float2 wB = *reinterpret_cast<const float2*>(wq + 2);
        const float2 wC = *reinterpret_cast<const float2*>(wq + 4);
        const float2 wD = *reinterpret_cast<const float2*>(wq + 6);
        const float2 wE = *reinterpret_cast<const float2*>(wq + 8);
        const float wr[10] = { wA.x, wA.y, wB.x, wB.y, wC.x, wC.y,
                               wD.x, wD.y, wE.x, wE.y };
        #pragma unroll
        for (int r = 0; r < 10; ++r)
            #pragma unroll
            for (int e = 0; e < 4; ++e) y[r][e] += wr[r] * pol[e][kk];
    }

    // ---- LN stats: butterfly over the 32-lane jg dimension ----
    float mu[4], rs[4];
    #pragma unroll
    for (int e = 0; e < 4; ++e) {
        float s = 0.f, q = 0.f;
        #pragma unroll
        for (int r = 0; r < 10; ++r) { s += y[r][e]; q += y[r][e] * y[r][e]; }
        s *= actf; q *= actf;
        #pragma unroll
        for (int o = 16; o > 0; o >>= 1) {
            s += __shfl_xor(s, o, 32);
            q += __shfl_xor(q, o, 32);
        }
        mu[e] = s * (1.f / 300.f);
        float var = q * (1.f / 300.f) - mu[e] * mu[e];
        rs[e] = rsqrtf(var + 1e-5f);
    }

    // ---- LN + relu + layer-2 partials + butterfly reduce ----
    const float2 gA = *reinterpret_cast<const float2*>(&g1[j0 + 0]);
    const float2 gB = *reinterpret_cast<const float2*>(&g1[j0 + 2]);
    const float2 gC = *reinterpret_cast<const float2*>(&g1[j0 + 4]);
    const float2 gD = *reinterpret_cast<const float2*>(&g1[j0 + 6]);
    const float2 gE = *reinterpret_cast<const float2*>(&g1[j0 + 8]);
    const float2 eA = *reinterpret_cast<const float2*>(&be1[j0 + 0]);
    const float2 eB = *reinterpret_cast<const float2*>(&be1[j0 + 2]);
    const float2 eC = *reinterpret_cast<const float2*>(&be1[j0 + 4]);
    const float2 eD = *reinterpret_cast<const float2*>(&be1[j0 + 6]);
    const float2 eE = *reinterpret_cast<const float2*>(&be1[j0 + 8]);
    const float gr[10] = { gA.x, gA.y, gB.x, gB.y, gC.x, gC.y, gD.x, gD.y, gE.x, gE.y };
    const float er[10] = { eA.x, eA.y, eB.x, eB.y, eC.x, eC.y, eD.x, eD.y, eE.x, eE.y };
    float w20[10], w21[10];
    #pragma unroll
    for (int r = 0; r < 10; ++r) {
        const float2 w2 = *reinterpret_cast<const float2*>(&W2[(j0 + r) * 2]);
        w20[r] = w2.x; w21[r] = w2.y;
    }
    float o0[4], o1[4];
    #pragma unroll
    for (int e = 0; e < 4; ++e) {
        float s0 = 0.f, s1 = 0.f;
        #pragma unroll
        for (int r = 0; r < 10; ++r) {
            float yy = fmaxf((y[r][e] - mu[e]) * rs[e] * gr[r] + er[r], 0.f);
            s0 += yy * w20[r];
            s1 += yy * w21[r];
        }
        s0 *= actf; s1 *= actf;
        #pragma unroll
        for (int o = 16; o > 0; o >>= 1) {
            s0 += __shfl_xor(s0, o, 32);
            s1 += __shfl_xor(s1, o, 32);
        }
        o0[e] = s0; o1[e] = s1;
    }
    if (jg == 0) {
        const float b20 = b2[0], b21 = b2[1];
        #pragma unroll
        for (int e = 0; e < 4; ++e)
            *reinterpret_cast<float2*>(&eout[(size_t)(e0 + eb + e) * 2]) =
                make_float2(o0[e] + b20, o1[e] + b21);
    }
}

// ---------------------------------------------------------------------------
extern "C" void kernel_launch(void* const* d_in, const int* in_sizes, int n_in,
                              void* d_out, int out_size, void* d_ws, size_t ws_size,
                              hipStream_t stream)
{
    const float* h     = (const float*)d_in[0];
    const int*   src   = (const int*)d_in[1];
    const int*   dst   = (const int*)d_in[2];
    const int*   pos   = (const int*)d_in[3];
    const float* dist  = (const float*)d_in[4];
    const float* polar = (const float*)d_in[5];
    const float* Wp0   = (const float*)d_in[6];
    const float* bp0   = (const float*)d_in[7];
    const float* gp0   = (const float*)d_in[8];
    const float* bep0  = (const float*)d_in[9];
    const float* Wp1   = (const float*)d_in[10];
    const float* bp1   = (const float*)d_in[11];
    const float* gp1   = (const float*)d_in[12];
    const float* bep1  = (const float*)d_in[13];
    const float* Wg    = (const float*)d_in[14];
    const float* bg    = (const float*)d_in[15];
    const float* gg    = (const float*)d_in[16];
    const float* beg   = (const float*)d_in[17];
    const float* Wn    = (const float*)d_in[18];
    const float* bn    = (const float*)d_in[19];
    const float* gn    = (const float*)d_in[20];
    const float* ben   = (const float*)d_in[21];
    const float* W1    = (const float*)d_in[22];
    const float* b1    = (const float*)d_in[23];
    const float* g1    = (const float*)d_in[24];
    const float* be1   = (const float*)d_in[25];
    const float* W2    = (const float*)d_in[26];
    const float* b2    = (const float*)d_in[27];

    float* ws  = (float*)d_ws;
    float* acc = ws + ACC_OFF;
    float* hp  = ws + HP_OFF;
    float* hg  = hp;                        // aliased (see k_gemm_hg comment)
    float* cls = ws + CLS_OFF;
    float* u   = acc;                       // reuse acc region after k_gemm_hg
    float* v   = acc + V_OFF;
    float* nout = (float*)d_out;            // 40000*5
    float* eout = (float*)d_out + 200000;   // 256000*2

    k_zero<<<2048, 256, 0, stream>>>((float4*)acc, ACC_FLOATS / 4);

    k_proj<<<2500, 192, 0, stream>>>(h, Wp0, bp0, gp0, bep0,
                                     Wp1, bp1, gp1, bep1, hp);
    k_scatter<<<96000, 256, 0, stream>>>(hp, src, dst, pos, dist, acc);
    k_gemm_hg<<<1250, 256, 0, stream>>>(hp, acc, Wg, bg, gg, beg, hg);
    k_node_head<<<10000, 256, 0, stream>>>(hg, Wn, bn, gn, ben, nout, cls);
    k_node_uv<<<1250, 256, 0, stream>>>(hg, cls, W1, u, v);
    k_edge_small<<<8000, 256, 0, stream>>>(u, v, src, dst, polar,
                                           W1, b1, g1, be1, W2, b2, eout);
}